// Round 1
// baseline (568.107 us; speedup 1.0000x reference)
//
#include <hip/hip_runtime.h>
#include <math.h>

#define B 8
#define T 200
#define U 50
#define V 1024

__device__ __forceinline__ float wave_max(float v) {
    #pragma unroll
    for (int off = 32; off > 0; off >>= 1)
        v = fmaxf(v, __shfl_xor(v, off, 64));
    return v;
}
__device__ __forceinline__ float wave_sum(float v) {
    #pragma unroll
    for (int off = 32; off > 0; off >>= 1)
        v += __shfl_xor(v, off, 64);
    return v;
}

// One wave (64 threads) per (b,u). Computes logsumexp over t of the blank
// column (v=0) and the emit column (v=targets[b][u]), writes normalized
// log-probs t-contiguous into workspace.
__global__ void lse_kernel(const float* __restrict__ h,
                           const int* __restrict__ targets,
                           float* __restrict__ blank_ws,   // [B][U][T]
                           float* __restrict__ emit_ws) {  // [B][U-1][T]
    const int u = blockIdx.x;     // 0..U-1
    const int b = blockIdx.y;     // 0..B-1
    const int lane = threadIdx.x; // 0..63

    for (int which = 0; which < 2; ++which) {
        int v;
        if (which == 0) {
            v = 0;
        } else {
            if (u >= U - 1) break;
            v = targets[b * (U - 1) + u];
        }
        // h[b][t][u][v], stride over t = U*V
        const float* base = h + (size_t)b * T * U * V + (size_t)u * V + v;
        float x[4];
        float m = -INFINITY;
        #pragma unroll
        for (int k = 0; k < 4; ++k) {
            int t = lane + 64 * k;
            x[k] = (t < T) ? base[(size_t)t * U * V] : -INFINITY;
            m = fmaxf(m, x[k]);
        }
        m = wave_max(m);
        float s = 0.f;
        #pragma unroll
        for (int k = 0; k < 4; ++k)
            s += expf(x[k] - m);   // x[k] = -inf contributes 0
        s = wave_sum(s);
        float lse = m + logf(s);
        float* out = (which == 0)
            ? blank_ws + ((size_t)b * U + u) * T
            : emit_ws + ((size_t)b * (U - 1) + u) * T;
        #pragma unroll
        for (int k = 0; k < 4; ++k) {
            int t = lane + 64 * k;
            if (t < T) out[t] = x[k] - lse;
        }
    }
}

// One wave per batch element. Anti-diagonal wavefront: lane u holds
// alpha[d-u][u]; alpha[t][u-1] (same previous diagonal) comes from lane u-1
// via shfl_up. Recursion:
//   alpha[t][u] = logaddexp(alpha[t-1][u] + blank[t-1][u],
//                           alpha[t][u-1] + emit[t][u-1]),  alpha[0][0] = 0.
__global__ void dp_kernel(const float* __restrict__ blank_ws,
                          const float* __restrict__ emit_ws,
                          const int* __restrict__ input_lens,
                          const int* __restrict__ target_lens,
                          float* __restrict__ neg_final) {
    const int b = blockIdx.x;
    const int u = threadIdx.x; // lane == u
    const float* bl = blank_ws + ((size_t)b * U + u) * T;       // bl[t], valid u<U
    const float* em = emit_ws + (size_t)b * (U - 1) * T;        // em[(u-1)*T + t]
    const int ti = input_lens[b] - 1;
    const int ui = target_lens[b] - 1;

    float a_prev = -INFINITY;
    float result = -INFINITY;
    const int D = T + U - 1;
    for (int d = 0; d < D; ++d) {
        const int t = d - u;
        const float left = __shfl_up(a_prev, 1, 64); // lane u-1's prev-diag value
        const bool cell = (t >= 0) && (t < T) && (u < U);
        float term1 = -INFINITY, term2 = -INFINITY;
        if (cell && t >= 1) term1 = a_prev + bl[t - 1];
        if (cell && u >= 1) term2 = left + em[(size_t)(u - 1) * T + t];
        float a_new;
        if (d == 0) {
            a_new = (u == 0) ? 0.f : -INFINITY;
        } else {
            const float mx = fmaxf(term1, term2);
            a_new = (mx == -INFINITY)
                ? -INFINITY
                : mx + log1pf(expf(fminf(term1, term2) - mx));
        }
        if (cell) a_prev = a_new;
        if (u == ui && t == ti) result = a_new;
    }
    if (u == ui) neg_final[b] = -(result + bl[ti]);
}

__global__ void mean_kernel(const float* __restrict__ neg_final,
                            float* __restrict__ out) {
    const int lane = threadIdx.x;
    float v = (lane < B) ? neg_final[lane] : 0.f;
    v = wave_sum(v);
    if (lane == 0) out[0] = v / (float)B;
}

extern "C" void kernel_launch(void* const* d_in, const int* in_sizes, int n_in,
                              void* d_out, int out_size, void* d_ws, size_t ws_size,
                              hipStream_t stream) {
    const float* h = (const float*)d_in[0];
    const int* targets = (const int*)d_in[1];
    const int* input_lens = (const int*)d_in[2];
    const int* target_lens = (const int*)d_in[3];
    float* out = (float*)d_out;

    float* blank_ws = (float*)d_ws;                  // B*U*T floats
    float* emit_ws = blank_ws + (size_t)B * U * T;   // B*(U-1)*T floats
    float* neg_final = emit_ws + (size_t)B * (U - 1) * T; // B floats

    dim3 g1(U, B);
    lse_kernel<<<g1, 64, 0, stream>>>(h, targets, blank_ws, emit_ws);
    dp_kernel<<<B, 64, 0, stream>>>(blank_ws, emit_ws, input_lens, target_lens, neg_final);
    mean_kernel<<<1, 64, 0, stream>>>(neg_final, out);
}

// Round 2
// 417.398 us; speedup vs baseline: 1.3611x; 1.3611x over previous
//
#include <hip/hip_runtime.h>
#include <math.h>

#define B 8
#define T 200
#define U 50
#define V 1024

__device__ __forceinline__ float wave_max(float v) {
    #pragma unroll
    for (int off = 32; off > 0; off >>= 1)
        v = fmaxf(v, __shfl_xor(v, off, 64));
    return v;
}
__device__ __forceinline__ float wave_sum(float v) {
    #pragma unroll
    for (int off = 32; off > 0; off >>= 1)
        v += __shfl_xor(v, off, 64);
    return v;
}

// One 256-thread block per (b,u): thread t gathers h[b,t,u,0] and
// h[b,t,u,tgt], block-reduces logsumexp over t, writes normalized log-probs
// t-contiguous into workspace. 256 threads => ~400 scattered loads in flight
// per block (vs 8/wave before) to hide HBM/TLB latency.
__global__ void lse_kernel(const float* __restrict__ h,
                           const int* __restrict__ targets,
                           float* __restrict__ blank_ws,   // [B][U][T]
                           float* __restrict__ emit_ws) {  // [B][U-1][T]
    const int u = blockIdx.x;
    const int b = blockIdx.y;
    const int t = threadIdx.x;          // 0..255, valid t < 200
    const int lane = t & 63;
    const int wid = t >> 6;             // 0..3

    __shared__ float s_part[4];

    // gather (issue both loads up front, independent)
    const size_t base = ((size_t)b * T + t) * U + u;
    float xb = -INFINITY, xe = -INFINITY;
    int tgt = 0;
    const bool do_emit = (u < U - 1);
    if (do_emit) tgt = targets[b * (U - 1) + u];
    if (t < T) {
        xb = h[base * V];               // v = 0 (blank)
        if (do_emit) xe = h[base * V + tgt];
    }

    // --- logsumexp over t for blank ---
    float m = wave_max(xb);
    if (lane == 0) s_part[wid] = m;
    __syncthreads();
    const float mb = fmaxf(fmaxf(s_part[0], s_part[1]), fmaxf(s_part[2], s_part[3]));
    __syncthreads();
    float s = wave_sum((t < T) ? __expf(xb - mb) : 0.f);
    if (lane == 0) s_part[wid] = s;
    __syncthreads();
    const float lse_b = mb + __logf(s_part[0] + s_part[1] + s_part[2] + s_part[3]);
    if (t < T) blank_ws[((size_t)b * U + u) * T + t] = xb - lse_b;

    if (do_emit) {
        __syncthreads();
        float me = wave_max(xe);
        if (lane == 0) s_part[wid] = me;
        __syncthreads();
        const float mE = fmaxf(fmaxf(s_part[0], s_part[1]), fmaxf(s_part[2], s_part[3]));
        __syncthreads();
        float se = wave_sum((t < T) ? __expf(xe - mE) : 0.f);
        if (lane == 0) s_part[wid] = se;
        __syncthreads();
        const float lse_e = mE + __logf(s_part[0] + s_part[1] + s_part[2] + s_part[3]);
        if (t < T) emit_ws[((size_t)b * (U - 1) + u) * T + t] = xe - lse_e;
    }
}

// One block per batch element. Stage the whole per-batch DP table into LDS
// (79.2 KB < 160 KB/CU), then wave 0 runs the anti-diagonal wavefront with
// lane == u; the (t, u-1) dependency is lane u-1's previous-diagonal value
// (one shfl_up). LDS read addresses depend only on the loop counter, so they
// schedule off the serial logaddexp chain.
__global__ void dp_kernel(const float* __restrict__ blank_ws,
                          const float* __restrict__ emit_ws,
                          const int* __restrict__ input_lens,
                          const int* __restrict__ target_lens,
                          float* __restrict__ neg_final) {
    __shared__ float s_bl[U * T];         // 10000 floats = 40 KB
    __shared__ float s_em[(U - 1) * T];   //  9800 floats = 39.2 KB

    const int b = blockIdx.x;
    const int tid = threadIdx.x;          // 0..255

    // coalesced float4 staging (both source blocks are 16B-aligned per b)
    {
        const float4* gb = (const float4*)(blank_ws + (size_t)b * U * T);
        float4* sb = (float4*)s_bl;
        #pragma unroll
        for (int i = tid; i < (U * T) / 4; i += 256) sb[i] = gb[i];
        const float4* ge = (const float4*)(emit_ws + (size_t)b * (U - 1) * T);
        float4* se = (float4*)s_em;
        #pragma unroll
        for (int i = tid; i < ((U - 1) * T) / 4; i += 256) se[i] = ge[i];
    }
    __syncthreads();

    if (tid >= 64) return;                // only wave 0 runs the DP
    const int u = tid;
    const int ti = input_lens[b] - 1;
    const int ui = target_lens[b] - 1;

    float a_prev = -INFINITY;
    float result = -INFINITY;
    const int D = T + U - 1;
    for (int d = 0; d < D; ++d) {
        const int t = d - u;
        const float left = __shfl_up(a_prev, 1, 64);
        const bool cell = (t >= 0) && (t < T) && (u < U);
        float term1 = -INFINITY, term2 = -INFINITY;
        if (cell && t >= 1) term1 = a_prev + s_bl[u * T + (t - 1)];
        if (cell && u >= 1) term2 = left + s_em[(u - 1) * T + t];
        float a_new;
        if (d == 0) {
            a_new = (u == 0) ? 0.f : -INFINITY;
        } else {
            const float mx = fmaxf(term1, term2);
            a_new = (mx == -INFINITY)
                ? -INFINITY
                : mx + __logf(1.f + __expf(fminf(term1, term2) - mx));
        }
        if (cell) a_prev = a_new;
        if (u == ui && t == ti) result = a_new;
    }
    if (u == ui) neg_final[b] = -(result + s_bl[ui * T + ti]);
}

__global__ void mean_kernel(const float* __restrict__ neg_final,
                            float* __restrict__ out) {
    const int lane = threadIdx.x;
    float v = (lane < B) ? neg_final[lane] : 0.f;
    v = wave_sum(v);
    if (lane == 0) out[0] = v / (float)B;
}

extern "C" void kernel_launch(void* const* d_in, const int* in_sizes, int n_in,
                              void* d_out, int out_size, void* d_ws, size_t ws_size,
                              hipStream_t stream) {
    const float* h = (const float*)d_in[0];
    const int* targets = (const int*)d_in[1];
    const int* input_lens = (const int*)d_in[2];
    const int* target_lens = (const int*)d_in[3];
    float* out = (float*)d_out;

    float* blank_ws = (float*)d_ws;                       // B*U*T floats
    float* emit_ws = blank_ws + (size_t)B * U * T;        // B*(U-1)*T floats
    float* neg_final = emit_ws + (size_t)B * (U - 1) * T; // B floats

    dim3 g1(U, B);
    lse_kernel<<<g1, 256, 0, stream>>>(h, targets, blank_ws, emit_ws);
    dp_kernel<<<B, 256, 0, stream>>>(blank_ws, emit_ws, input_lens, target_lens, neg_final);
    mean_kernel<<<1, 64, 0, stream>>>(neg_final, out);
}

// Round 3
// 412.539 us; speedup vs baseline: 1.3771x; 1.0118x over previous
//
#include <hip/hip_runtime.h>
#include <math.h>

#define B 8
#define T 200
#define U 50
#define V 1024

__device__ __forceinline__ float wave_max(float v) {
    #pragma unroll
    for (int off = 32; off > 0; off >>= 1)
        v = fmaxf(v, __shfl_xor(v, off, 64));
    return v;
}
__device__ __forceinline__ float wave_sum(float v) {
    #pragma unroll
    for (int off = 32; off > 0; off >>= 1)
        v += __shfl_xor(v, off, 64);
    return v;
}

// One 64-lane wave per (b, u, which): logsumexp over t of one column of h
// (v=0 blank, or v=targets[b][u] emit), normalized log-probs written
// t-contiguous to workspace. 800 fully-independent waves, no barriers, no
// serial blank->emit phase. Thread (0,0,0) also zeroes d_out for the dp
// kernel's atomic mean accumulation.
__global__ void lse_kernel(const float* __restrict__ h,
                           const int* __restrict__ targets,
                           float* __restrict__ blank_ws,   // [B][U][T]
                           float* __restrict__ emit_ws,    // [B][U-1][T]
                           float* __restrict__ out) {
    const int u = blockIdx.x;
    const int b = blockIdx.y;
    const int which = blockIdx.z;   // 0 = blank, 1 = emit
    const int lane = threadIdx.x;   // 0..63

    if (u == 0 && b == 0 && which == 0 && lane == 0) out[0] = 0.f;
    if (which == 1 && u >= U - 1) return;

    const int v = (which == 0) ? 0 : targets[b * (U - 1) + u];
    const float* base = h + (size_t)b * T * U * V + (size_t)u * V + v;

    float x[4];
    float m = -INFINITY;
    #pragma unroll
    for (int k = 0; k < 4; ++k) {
        const int t = lane + 64 * k;
        x[k] = (t < T) ? base[(size_t)t * U * V] : -INFINITY;
        m = fmaxf(m, x[k]);
    }
    m = wave_max(m);
    float s = 0.f;
    #pragma unroll
    for (int k = 0; k < 4; ++k)
        s += __expf(x[k] - m);      // -inf contributes 0
    s = wave_sum(s);
    const float lse = m + __logf(s);

    float* outp = (which == 0)
        ? blank_ws + ((size_t)b * U + u) * T
        : emit_ws + ((size_t)b * (U - 1) + u) * T;
    #pragma unroll
    for (int k = 0; k < 4; ++k) {
        const int t = lane + 64 * k;
        if (t < T) outp[t] = x[k] - lse;
    }
}

// One block per batch element. Stage the per-batch DP table into LDS
// (79.2 KB < 160 KB/CU) with coalesced float4 loads, then wave 0 runs the
// anti-diagonal wavefront (lane == u); the (t, u-1) dependency is lane u-1's
// previous-diagonal value via shfl_up. Fused mean: lane ui atomically adds
// -final/B into d_out (zeroed by lse_kernel, visible via stream ordering).
__global__ void dp_kernel(const float* __restrict__ blank_ws,
                          const float* __restrict__ emit_ws,
                          const int* __restrict__ input_lens,
                          const int* __restrict__ target_lens,
                          float* __restrict__ out) {
    __shared__ float s_bl[U * T];         // 40 KB
    __shared__ float s_em[(U - 1) * T];   // 39.2 KB

    const int b = blockIdx.x;
    const int tid = threadIdx.x;          // 0..255

    {
        const float4* gb = (const float4*)(blank_ws + (size_t)b * U * T);
        float4* sb = (float4*)s_bl;
        #pragma unroll 4
        for (int i = tid; i < (U * T) / 4; i += 256) sb[i] = gb[i];
        const float4* ge = (const float4*)(emit_ws + (size_t)b * (U - 1) * T);
        float4* se = (float4*)s_em;
        #pragma unroll 4
        for (int i = tid; i < ((U - 1) * T) / 4; i += 256) se[i] = ge[i];
    }
    __syncthreads();

    if (tid >= 64) return;                // wave 0 only
    const int u = tid;
    const int ti = input_lens[b] - 1;
    const int ui = target_lens[b] - 1;

    // d = 0: alpha[0][0] = 0
    float a_prev = (u == 0) ? 0.f : -INFINITY;
    float result = (u == 0 && ti == 0) ? 0.f : -INFINITY;

    const int D = T + U - 1;
    for (int d = 1; d < D; ++d) {
        const int t = d - u;
        const float left = __shfl_up(a_prev, 1, 64);
        const bool cell = (t >= 0) && (t < T) && (u < U);
        float term1 = -INFINITY, term2 = -INFINITY;
        if (cell && t >= 1) term1 = a_prev + s_bl[u * T + (t - 1)];
        if (cell && u >= 1) term2 = left + s_em[(u - 1) * T + t];
        const float mx = fmaxf(term1, term2);
        const float a_new = (mx == -INFINITY)
            ? -INFINITY
            : mx + __logf(1.f + __expf(fminf(term1, term2) - mx));
        if (cell) a_prev = a_new;
        if (u == ui && t == ti) result = a_new;
    }
    if (u == ui)
        atomicAdd(out, -(result + s_bl[ui * T + ti]) * (1.f / (float)B));
}

extern "C" void kernel_launch(void* const* d_in, const int* in_sizes, int n_in,
                              void* d_out, int out_size, void* d_ws, size_t ws_size,
                              hipStream_t stream) {
    const float* h = (const float*)d_in[0];
    const int* targets = (const int*)d_in[1];
    const int* input_lens = (const int*)d_in[2];
    const int* target_lens = (const int*)d_in[3];
    float* out = (float*)d_out;

    float* blank_ws = (float*)d_ws;                   // B*U*T floats
    float* emit_ws = blank_ws + (size_t)B * U * T;    // B*(U-1)*T floats

    dim3 g1(U, B, 2);
    lse_kernel<<<g1, 64, 0, stream>>>(h, targets, blank_ws, emit_ws, out);
    dp_kernel<<<B, 256, 0, stream>>>(blank_ws, emit_ws, input_lens, target_lens, out);
}